// Round 6
// baseline (476.330 us; speedup 1.0000x reference)
//
#include <hip/hip_runtime.h>
#include <hip/hip_bf16.h>
#include <math.h>

#define L 4096          // H*W
#define C 128
#define NH 4
#define HD 32
#define KS 4            // flash split-K factor
#define EPSV 1e-5f
#define NBLK 1024u      // fused grid: 4 blocks/CU x 256 CUs (flash's proven config)

typedef short bf16x8 __attribute__((ext_vector_type(8)));
typedef float f32x4 __attribute__((ext_vector_type(4)));

static __device__ __forceinline__ unsigned pack2bf(float a, float b) {
    __hip_bfloat162 h = __float22bfloat162_rn(make_float2(a, b));
    unsigned u; __builtin_memcpy(&u, &h, 4); return u;
}
static __device__ __forceinline__ float bf_lo(unsigned u) {
    unsigned v = u << 16; float f; __builtin_memcpy(&f, &v, 4); return f;
}
static __device__ __forceinline__ float bf_hi(unsigned u) {
    unsigned v = u & 0xffff0000u; float f; __builtin_memcpy(&f, &v, 4); return f;
}
// Fused Schraudolph-2^x + bf16-pack: y = x*2^7 + (2^23 + 127*2^7 - 6).
// Low 16 mantissa bits of y ARE bf16(2^x). 3 VALU per pair (passed r5,
// absmax unchanged at 0.015625).
static __device__ __forceinline__ unsigned exp2pk(float a, float b) {
    float fa = fmaf(a, 128.f, 8404858.f);
    float fb = fmaf(b, 128.f, 8404858.f);
    unsigned ua, ub;
    __builtin_memcpy(&ua, &fa, 4);
    __builtin_memcpy(&ub, &fb, 4);
    return __builtin_amdgcn_perm(ub, ua, 0x05040100);  // (ua&0xffff)|(ub<<16)
}

// Device-scope grid barrier: release-add, acquire-spin (thread 0), block-wide
// via __syncthreads. AGENT scope handles cross-XCD L2 non-coherence (release
// writes back producer stores; acquire invalidates stale lines).
static __device__ __forceinline__ void grid_barrier(unsigned* c, unsigned nb) {
    __syncthreads();
    if (threadIdx.x == 0) {
        __hip_atomic_fetch_add(c, 1u, __ATOMIC_RELEASE, __HIP_MEMORY_SCOPE_AGENT);
        while (__hip_atomic_load(c, __ATOMIC_ACQUIRE, __HIP_MEMORY_SCOPE_AGENT) < nb)
            __builtin_amdgcn_s_sleep(2);
    }
    __syncthreads();
}

// ---------------------------------------------------------------------------
// Fused pipeline: [gn_stats | proj | flash | final] with 3 grid barriers.
// One dispatch instead of four — attacks the measured ~40-50us of launch/
// serialization overhead in the 4-deep dependent chain. Phase bodies are
// byte-identical to the r5 production kernels; blockIdx decompositions are
// mapped onto the linear bid. LDS is one 18432B arena (flash's Ps = max).
__global__ __launch_bounds__(256, 4) void fused_kernel(
    const float* __restrict__ x, const float* __restrict__ ctx,
    const float* __restrict__ gq, const float* __restrict__ bq,
    const float* __restrict__ gctx, const float* __restrict__ bctx,
    const float* __restrict__ Wq, const float* __restrict__ Wk,
    const float* __restrict__ Wv, const float* __restrict__ Wout,
    const float* __restrict__ bout, const float* __restrict__ alpha,
    unsigned short* __restrict__ Qt, unsigned short* __restrict__ Kt,
    unsigned short* __restrict__ Vsw, unsigned short* __restrict__ Po,
    float* __restrict__ Pl, float* __restrict__ stats,
    unsigned* __restrict__ bar, float* __restrict__ out)
{
    __shared__ __attribute__((aligned(16))) unsigned char SMEM[4 * 2 * 1152 * 2];
    int bid = blockIdx.x;
    int t = threadIdx.x;

    // ---------------- Phase 0: GroupNorm partial sums (512 units) ----------
    if (bid < 512) {
        const float* in = (bid < 256) ? x : ctx;
        int idx = bid & 255;                   // (b*32+g)*4 + qtr
        const float4* p = (const float4*)(in + (size_t)(idx >> 2) * 16384
                                             + (size_t)(idx & 3) * 4096);
        float s = 0.f, s2 = 0.f;
        #pragma unroll
        for (int rr = 0; rr < 4; rr++) {
            float4 v = p[t + rr * 256];
            s  += v.x + v.y + v.z + v.w;
            s2 += v.x*v.x + v.y*v.y + v.z*v.z + v.w*v.w;
        }
        #pragma unroll
        for (int m = 32; m >= 1; m >>= 1) {
            s  += __shfl_xor(s, m);
            s2 += __shfl_xor(s2, m);
        }
        float (*wsum)[2] = (float(*)[2])SMEM;
        int w = t >> 6;
        if ((t & 63) == 0) { wsum[w][0] = s; wsum[w][1] = s2; }
        __syncthreads();
        if (t == 0) {
            float S  = wsum[0][0] + wsum[1][0] + wsum[2][0] + wsum[3][0];
            float S2 = wsum[0][1] + wsum[1][1] + wsum[2][1] + wsum[3][1];
            stats[bid * 2]     = S;
            stats[bid * 2 + 1] = S2;
        }
    }
    grid_barrier(&bar[0], NBLK);

    // ---------------- Phase 1: GN + 1x1 conv projections (768 units) -------
    if (bid < 768) {
        int w = t >> 6, lane = t & 63, n16 = lane & 15, quad = lane >> 4;
        int bx = bid & 127, by = (bid >> 7) & 1, bz = bid >> 8;
        int dtile = bx * 32;
        int b = by, z = bz;

        const float* in; const float* Wm; const float* gamma; const float* beta;
        int sel = 1, donorm = 1; float oscale = 1.f;
        if (z == 0)      { in = x;   Wm = Wq; gamma = gq;   beta = bq;   sel = 0;
                           oscale = 0.17677669529663689f * 1.4426950408889634f; }
        else if (z == 1) { in = ctx; Wm = Wk; gamma = gctx; beta = bctx; }
        else             { in = ctx; Wm = Wv; gamma = 0;    beta = 0;    donorm = 0; }

        unsigned short* Xs = (unsigned short*)SMEM;   // [32 d][136 c]

        // stage 128c x 32d tile: GN + bf16 + 4x4 register transpose
        {
            int c0 = (t >> 3) * 4, d4 = (t & 7) * 4;
            const float* inb = in + (size_t)b * (C * L);
            float scg[4], shg[4];
            if (donorm) {
                int gl = (sel * 256 + (b * 32 + (c0 >> 2)) * 4) * 2;
                float S  = stats[gl] + stats[gl + 2] + stats[gl + 4] + stats[gl + 6];
                float S2 = stats[gl + 1] + stats[gl + 3] + stats[gl + 5] + stats[gl + 7];
                float mean = S * (1.f / 16384.f);
                float var  = S2 * (1.f / 16384.f) - mean * mean;
                float inv  = rsqrtf(var + EPSV);
                #pragma unroll
                for (int j = 0; j < 4; j++) {
                    scg[j] = inv * gamma[c0 + j];
                    shg[j] = beta[c0 + j] - mean * scg[j];
                }
            } else {
                #pragma unroll
                for (int j = 0; j < 4; j++) { scg[j] = 1.f; shg[j] = 0.f; }
            }
            float vv[4][4];
            #pragma unroll
            for (int j = 0; j < 4; j++) {
                float4 v = *(const float4*)(inb + (size_t)(c0 + j) * L + dtile + d4);
                vv[j][0] = v.x * scg[j] + shg[j]; vv[j][1] = v.y * scg[j] + shg[j];
                vv[j][2] = v.z * scg[j] + shg[j]; vv[j][3] = v.w * scg[j] + shg[j];
            }
            #pragma unroll
            for (int i = 0; i < 4; i++) {
                uint2 pk;
                pk.x = pack2bf(vv[0][i], vv[1][i]);
                pk.y = pack2bf(vv[2][i], vv[3][i]);
                *(uint2*)&Xs[(d4 + i) * 136 + c0] = pk;
            }
        }

        // W A-fragments: wave w covers o-strips {w, w+4}; A[m=o][k=c]
        bf16x8 wa[2][4];
        #pragma unroll
        for (int os2 = 0; os2 < 2; os2++) {
            const float* wr = Wm + (size_t)(((w + os2 * 4) * 16) + n16) * C + quad * 8;
            #pragma unroll
            for (int kk = 0; kk < 4; kk++) {
                float4 a  = *(const float4*)(wr + kk * 32);
                float4 b2 = *(const float4*)(wr + kk * 32 + 4);
                unsigned u4[4] = { pack2bf(a.x, a.y),  pack2bf(a.z, a.w),
                                   pack2bf(b2.x, b2.y), pack2bf(b2.z, b2.w) };
                __builtin_memcpy(&wa[os2][kk], u4, 16);
            }
        }
        __syncthreads();

        f32x4 zero = {0.f, 0.f, 0.f, 0.f};
        f32x4 acc[2][2];
        acc[0][0] = zero; acc[0][1] = zero; acc[1][0] = zero; acc[1][1] = zero;
        #pragma unroll
        for (int kk = 0; kk < 4; kk++) {
            #pragma unroll
            for (int dg = 0; dg < 2; dg++) {
                bf16x8 xb;
                uint4 u = *(const uint4*)&Xs[(dg * 16 + n16) * 136 + kk * 32 + quad * 8];
                __builtin_memcpy(&xb, &u, 16);
                acc[0][dg] = __builtin_amdgcn_mfma_f32_16x16x32_bf16(wa[0][kk], xb, acc[0][dg], 0, 0, 0);
                acc[1][dg] = __builtin_amdgcn_mfma_f32_16x16x32_bf16(wa[1][kk], xb, acc[1][dg], 0, 0, 0);
            }
        }

        // epilogue: lane holds D[o = (w+os2*4)*16+quad*4+r][d = dtile+dg*16+n16]
        #pragma unroll
        for (int os2 = 0; os2 < 2; os2++) {
            int o = ((w + os2 * 4) * 16) + quad * 4;
            int h = o >> 5, c32 = o & 31;
            #pragma unroll
            for (int dg = 0; dg < 2; dg++) {
                int d = dtile + dg * 16 + n16;
                if (z < 2) {
                    unsigned short* outp = (z == 0) ? Qt : Kt;
                    uint2 pk;
                    pk.x = pack2bf(acc[os2][dg][0] * oscale, acc[os2][dg][1] * oscale);
                    pk.y = pack2bf(acc[os2][dg][2] * oscale, acc[os2][dg][3] * oscale);
                    *(uint2*)(outp + ((size_t)(b * NH + h) * L + d) * HD + c32) = pk;
                } else {
                    unsigned short* vb = Vsw + (size_t)(b * NH + h) * (L * HD)
                                       + (size_t)(d >> 3) * 256 + (d & 7);
                    #pragma unroll
                    for (int r = 0; r < 4; r++) {
                        __hip_bfloat16 hv = __float2bfloat16(acc[os2][dg][r]);
                        unsigned short us; __builtin_memcpy(&us, &hv, 2);
                        vb[(c32 + r) * 8] = us;
                    }
                }
            }
        }
    }
    grid_barrier(&bar[1], NBLK);

    // ---------------- Phase 2: flash attention (1024 units) -----------------
    {
        unsigned short* Ps = (unsigned short*)SMEM;   // [4 waves][2 sp][1152]
        int w = t >> 6, lane = t & 63;
        int n16 = lane & 15, quad = lane >> 4;
        int bh = bid & 7;
        int qbase = ((bid >> 3) & 31) * 128 + w * 32;
        int ks = bid >> 8;
        size_t hb = (size_t)bh * (L * HD);

        bf16x8 qf[2];
        #pragma unroll
        for (int sp = 0; sp < 2; sp++) {
            uint4 u = *(const uint4*)(Qt + hb + (size_t)(qbase + sp * 16 + n16) * HD + quad * 8);
            __builtin_memcpy(&qf[sp], &u, 16);
        }

        bf16x8 onesf;
        #pragma unroll
        for (int j = 0; j < 8; j++) onesf[j] = (short)0x3F80;

        const unsigned short* kfp = Kt + hb + (size_t)n16 * HD + quad * 8;
        const unsigned short* vfp = Vsw + hb + quad * 256 + n16 * 8;

        int e0 = ks * (L / KS);

        bf16x8 ka[2][4], va[2][4];
        #pragma unroll
        for (int et = 0; et < 4; et++) {
            uint4 u = *(const uint4*)(kfp + (size_t)(e0 + et * 16) * HD);
            __builtin_memcpy(&ka[0][et], &u, 16);
        }
        #pragma unroll
        for (int es = 0; es < 2; es++)
            #pragma unroll
            for (int f = 0; f < 2; f++) {
                uint4 u = *(const uint4*)(vfp + (size_t)(e0 + es * 32) * 32 + f * 128);
                __builtin_memcpy(&va[0][es * 2 + f], &u, 16);
            }

        f32x4 zero = {0.f, 0.f, 0.f, 0.f};
        f32x4 oacc[2][2], lacc[2];
        oacc[0][0] = zero; oacc[0][1] = zero; oacc[1][0] = zero; oacc[1][1] = zero;
        lacc[0] = zero; lacc[1] = zero;

        #pragma unroll 2
        for (int kt = 0; kt < L / KS / 64; kt++) {
            int cur = kt & 1, nxt = cur ^ 1;
            int enxt = e0 + (kt + 1) * 64;
            #pragma unroll
            for (int et = 0; et < 4; et++) {
                uint4 u = *(const uint4*)(kfp + (size_t)(enxt + et * 16) * HD);
                __builtin_memcpy(&ka[nxt][et], &u, 16);
            }
            #pragma unroll
            for (int es = 0; es < 2; es++)
                #pragma unroll
                for (int f = 0; f < 2; f++) {
                    uint4 u = *(const uint4*)(vfp + (size_t)(enxt + es * 32) * 32 + f * 128);
                    __builtin_memcpy(&va[nxt][es * 2 + f], &u, 16);
                }

            #pragma unroll
            for (int sp = 0; sp < 2; sp++) {
                f32x4 s[4];
                #pragma unroll
                for (int et = 0; et < 4; et++)
                    s[et] = __builtin_amdgcn_mfma_f32_16x16x32_bf16(ka[cur][et], qf[sp], zero, 0, 0, 0);
                unsigned short* pw = Ps + ((w * 2 + sp) * 1152) + n16 * 72;
                #pragma unroll
                for (int et = 0; et < 4; et++) {
                    uint2 pk;
                    pk.x = exp2pk(s[et][0], s[et][1]);
                    pk.y = exp2pk(s[et][2], s[et][3]);
                    *(uint2*)(pw + et * 16 + quad * 4) = pk;
                }
            }

            #pragma unroll
            for (int sp = 0; sp < 2; sp++) {
                unsigned short* pw = Ps + ((w * 2 + sp) * 1152) + n16 * 72;
                #pragma unroll
                for (int es = 0; es < 2; es++) {
                    bf16x8 pf;
                    uint4 u = *(const uint4*)(pw + es * 32 + quad * 8);
                    __builtin_memcpy(&pf, &u, 16);
                    oacc[sp][0] = __builtin_amdgcn_mfma_f32_16x16x32_bf16(va[cur][es * 2 + 0], pf, oacc[sp][0], 0, 0, 0);
                    oacc[sp][1] = __builtin_amdgcn_mfma_f32_16x16x32_bf16(va[cur][es * 2 + 1], pf, oacc[sp][1], 0, 0, 0);
                    lacc[sp]    = __builtin_amdgcn_mfma_f32_16x16x32_bf16(onesf, pf, lacc[sp], 0, 0, 0);
                }
            }
        }

        #pragma unroll
        for (int sp = 0; sp < 2; sp++) {
            int dq = qbase + sp * 16 + n16;
            unsigned short* po = Po + ((size_t)(bh * KS + ks) * L + dq) * 32;
            uint2 pk0, pk1;
            pk0.x = pack2bf(oacc[sp][0][0], oacc[sp][0][1]);
            pk0.y = pack2bf(oacc[sp][0][2], oacc[sp][0][3]);
            pk1.x = pack2bf(oacc[sp][1][0], oacc[sp][1][1]);
            pk1.y = pack2bf(oacc[sp][1][2], oacc[sp][1][3]);
            *(uint2*)(po + quad * 4)      = pk0;
            *(uint2*)(po + 16 + quad * 4) = pk1;
            if (quad == 0)
                Pl[(size_t)(bh * KS + ks) * L + dq] = lacc[sp][0];
        }
    }
    grid_barrier(&bar[2], NBLK);

    // ---------------- Phase 3: split-K combine + out GEMM + residual --------
    if (bid < 512) {
        int w = t >> 6, lane = t & 63, n16 = lane & 15, quad = lane >> 4;
        int dtile = (bid & 255) * 16;
        int b = bid >> 8;

        float* Ot = (float*)SMEM;                   // [128 o][20 d]
        unsigned short* Xs = (unsigned short*)SMEM; // [16 d][136 c]

        // stage: combine KS bf16 partials, normalize, bf16, [d][c] layout
        {
            int d_l = t >> 4, c0 = (t & 15) * 8;
            int dq = dtile + d_l;
            int bh = b * NH + (c0 >> 5);
            int c32 = c0 & 31;
            float l = 0.f;
            float o8[8] = {0.f, 0.f, 0.f, 0.f, 0.f, 0.f, 0.f, 0.f};
            #pragma unroll
            for (int ks = 0; ks < KS; ks++) {
                size_t base = (size_t)(bh * KS + ks) * L + dq;
                l += Pl[base];
                uint4 u = *(const uint4*)(Po + base * 32 + c32);
                o8[0] += bf_lo(u.x); o8[1] += bf_hi(u.x);
                o8[2] += bf_lo(u.y); o8[3] += bf_hi(u.y);
                o8[4] += bf_lo(u.z); o8[5] += bf_hi(u.z);
                o8[6] += bf_lo(u.w); o8[7] += bf_hi(u.w);
            }
            float rl = 1.f / l;
            uint4 pk;
            pk.x = pack2bf(o8[0] * rl, o8[1] * rl);
            pk.y = pack2bf(o8[2] * rl, o8[3] * rl);
            pk.z = pack2bf(o8[4] * rl, o8[5] * rl);
            pk.w = pack2bf(o8[6] * rl, o8[7] * rl);
            *(uint4*)&Xs[d_l * 136 + c0] = pk;
        }

        // Wout A-fragments
        bf16x8 wa[2][4];
        #pragma unroll
        for (int os2 = 0; os2 < 2; os2++) {
            const float* wr = Wout + (size_t)(((w + os2 * 4) * 16) + n16) * C + quad * 8;
            #pragma unroll
            for (int kk = 0; kk < 4; kk++) {
                float4 a  = *(const float4*)(wr + kk * 32);
                float4 b2 = *(const float4*)(wr + kk * 32 + 4);
                unsigned u4[4] = { pack2bf(a.x, a.y),  pack2bf(a.z, a.w),
                                   pack2bf(b2.x, b2.y), pack2bf(b2.z, b2.w) };
                __builtin_memcpy(&wa[os2][kk], u4, 16);
            }
        }
        __syncthreads();

        f32x4 zero = {0.f, 0.f, 0.f, 0.f};
        f32x4 acc[2];
        acc[0] = zero; acc[1] = zero;
        #pragma unroll
        for (int kk = 0; kk < 4; kk++) {
            bf16x8 xb;
            uint4 u = *(const uint4*)&Xs[n16 * 136 + kk * 32 + quad * 8];
            __builtin_memcpy(&xb, &u, 16);
            acc[0] = __builtin_amdgcn_mfma_f32_16x16x32_bf16(wa[0][kk], xb, acc[0], 0, 0, 0);
            acc[1] = __builtin_amdgcn_mfma_f32_16x16x32_bf16(wa[1][kk], xb, acc[1], 0, 0, 0);
        }
        __syncthreads();   // Xs reads done before Ot overwrite

        // acc -> Ot[o][d] (fp32, stride 20)
        #pragma unroll
        for (int os2 = 0; os2 < 2; os2++) {
            int o = ((w + os2 * 4) * 16) + quad * 4;
            #pragma unroll
            for (int r = 0; r < 4; r++)
                Ot[(o + r) * 20 + n16] = acc[os2][r];
        }
        __syncthreads();

        // epilogue: coalesced residual + store
        float al = alpha[0];
        int o = t >> 1, dh = (t & 1) * 8;
        float bo = bout[o];
        const float* xb2 = x + ((size_t)b * C + o) * L + dtile + dh;
        float* ob = out + ((size_t)b * C + o) * L + dtile + dh;
        #pragma unroll
        for (int jj = 0; jj < 2; jj++) {
            float4 a  = *(const float4*)&Ot[o * 20 + dh + jj * 4];
            float4 xv = *(const float4*)(xb2 + jj * 4);
            float4 r;
            r.x = xv.x + al * (a.x + bo);
            r.y = xv.y + al * (a.y + bo);
            r.z = xv.z + al * (a.z + bo);
            r.w = xv.w + al * (a.w + bo);
            *(float4*)(ob + jj * 4) = r;
        }
    }
}

// ---------------------------------------------------------------------------
extern "C" void kernel_launch(void* const* d_in, const int* in_sizes, int n_in,
                              void* d_out, int out_size, void* d_ws, size_t ws_size,
                              hipStream_t stream) {
    const float* x     = (const float*)d_in[0];
    const float* ctx   = (const float*)d_in[1];
    const float* gq    = (const float*)d_in[2];
    const float* bq    = (const float*)d_in[3];
    const float* gctx  = (const float*)d_in[4];
    const float* bctx  = (const float*)d_in[5];
    const float* Wq    = (const float*)d_in[6];
    const float* Wk    = (const float*)d_in[7];
    const float* Wv    = (const float*)d_in[8];
    const float* Wout  = (const float*)d_in[9];
    const float* bout  = (const float*)d_in[10];
    const float* alpha = (const float*)d_in[11];
    float* out = (float*)d_out;

    char* ws = (char*)d_ws;
    unsigned short* Qt  = (unsigned short*)(ws);              //  2 MB
    unsigned short* Kt  = (unsigned short*)(ws + 2097152);    //  2 MB
    unsigned short* Vsw = (unsigned short*)(ws + 4194304);    //  2 MB
    unsigned short* Po  = (unsigned short*)(ws + 6291456);    //  8 MB (bf16, KS=4)
    float*          Pl  = (float*)(ws + 14680064);            //  512 KB
    float*          stats = (float*)(ws + 15204352);          //  4 KB (512 x 2)
    unsigned*       bar = (unsigned*)(ws + 15728640);         //  64 B barrier ctrs

    // zero barrier counters (capture-safe stream op; re-runs every iteration)
    hipMemsetAsync(bar, 0, 64, stream);
    fused_kernel<<<NBLK, 256, 0, stream>>>(x, ctx, gq, bq, gctx, bctx,
                                           Wq, Wk, Wv, Wout, bout, alpha,
                                           Qt, Kt, Vsw, Po, Pl, stats, bar, out);
}

// Round 7
// 403.571 us; speedup vs baseline: 1.1803x; 1.1803x over previous
//
#include <hip/hip_runtime.h>
#include <hip/hip_bf16.h>
#include <math.h>

#define L 4096          // H*W
#define C 128
#define NH 4
#define HD 32
#define KS 4            // flash split-K factor
#define EPSV 1e-5f
#define NBLK 1024u      // fused grid: 4 blocks/CU x 256 CUs (flash's proven config)

typedef short bf16x8 __attribute__((ext_vector_type(8)));
typedef float f32x4 __attribute__((ext_vector_type(4)));

static __device__ __forceinline__ unsigned pack2bf(float a, float b) {
    __hip_bfloat162 h = __float22bfloat162_rn(make_float2(a, b));
    unsigned u; __builtin_memcpy(&u, &h, 4); return u;
}
static __device__ __forceinline__ float bf_lo(unsigned u) {
    unsigned v = u << 16; float f; __builtin_memcpy(&f, &v, 4); return f;
}
static __device__ __forceinline__ float bf_hi(unsigned u) {
    unsigned v = u & 0xffff0000u; float f; __builtin_memcpy(&f, &v, 4); return f;
}
// Fused Schraudolph-2^x + bf16-pack: y = x*2^7 + (2^23 + 127*2^7 - 6).
// Low 16 mantissa bits of y ARE bf16(2^x). 3 VALU per pair (passed r5/r6,
// absmax unchanged at 0.015625).
static __device__ __forceinline__ unsigned exp2pk(float a, float b) {
    float fa = fmaf(a, 128.f, 8404858.f);
    float fb = fmaf(b, 128.f, 8404858.f);
    unsigned ua, ub;
    __builtin_memcpy(&ua, &fa, 4);
    __builtin_memcpy(&ub, &fb, 4);
    return __builtin_amdgcn_perm(ub, ua, 0x05040100);  // (ua&0xffff)|(ub<<16)
}

// Grid barrier, r7 fix: RELAXED spin (no per-poll cache invalidate — r6's
// ACQUIRE-per-poll emitted buffer_inv each iteration, 1024 spinners x inv
// storm = 418us kernel at 2% util) + ONE agent acquire-fence after exit.
// Release on the arrive-add publishes producer stores (L2 writeback, once
// per block); the single post-spin fence invalidates stale lines for the
// consumer phase. Thread-0-only, fanned out via __syncthreads (visibility
// structure identical to r6, which passed correctness).
static __device__ __forceinline__ void grid_barrier(unsigned* c, unsigned nb) {
    __syncthreads();
    if (threadIdx.x == 0) {
        __hip_atomic_fetch_add(c, 1u, __ATOMIC_RELEASE, __HIP_MEMORY_SCOPE_AGENT);
        while (__hip_atomic_load(c, __ATOMIC_RELAXED, __HIP_MEMORY_SCOPE_AGENT) < nb)
            __builtin_amdgcn_s_sleep(16);
        __builtin_amdgcn_fence(__ATOMIC_ACQUIRE, "agent");
    }
    __syncthreads();
}

// ---------------------------------------------------------------------------
// Fused pipeline: [gn_stats | proj | flash | final] with 3 grid barriers.
// One dispatch instead of four. Phase bodies byte-identical to the r5
// production kernels; blockIdx decompositions mapped onto the linear bid.
// LDS is one 18432B arena (flash's Ps = max).
__global__ __launch_bounds__(256, 4) void fused_kernel(
    const float* __restrict__ x, const float* __restrict__ ctx,
    const float* __restrict__ gq, const float* __restrict__ bq,
    const float* __restrict__ gctx, const float* __restrict__ bctx,
    const float* __restrict__ Wq, const float* __restrict__ Wk,
    const float* __restrict__ Wv, const float* __restrict__ Wout,
    const float* __restrict__ bout, const float* __restrict__ alpha,
    unsigned short* __restrict__ Qt, unsigned short* __restrict__ Kt,
    unsigned short* __restrict__ Vsw, unsigned short* __restrict__ Po,
    float* __restrict__ Pl, float* __restrict__ stats,
    unsigned* __restrict__ bar, float* __restrict__ out)
{
    __shared__ __attribute__((aligned(16))) unsigned char SMEM[4 * 2 * 1152 * 2];
    int bid = blockIdx.x;
    int t = threadIdx.x;

    // ---------------- Phase 0: GroupNorm partial sums (512 units) ----------
    if (bid < 512) {
        const float* in = (bid < 256) ? x : ctx;
        int idx = bid & 255;                   // (b*32+g)*4 + qtr
        const float4* p = (const float4*)(in + (size_t)(idx >> 2) * 16384
                                             + (size_t)(idx & 3) * 4096);
        float s = 0.f, s2 = 0.f;
        #pragma unroll
        for (int rr = 0; rr < 4; rr++) {
            float4 v = p[t + rr * 256];
            s  += v.x + v.y + v.z + v.w;
            s2 += v.x*v.x + v.y*v.y + v.z*v.z + v.w*v.w;
        }
        #pragma unroll
        for (int m = 32; m >= 1; m >>= 1) {
            s  += __shfl_xor(s, m);
            s2 += __shfl_xor(s2, m);
        }
        float (*wsum)[2] = (float(*)[2])SMEM;
        int w = t >> 6;
        if ((t & 63) == 0) { wsum[w][0] = s; wsum[w][1] = s2; }
        __syncthreads();
        if (t == 0) {
            float S  = wsum[0][0] + wsum[1][0] + wsum[2][0] + wsum[3][0];
            float S2 = wsum[0][1] + wsum[1][1] + wsum[2][1] + wsum[3][1];
            stats[bid * 2]     = S;
            stats[bid * 2 + 1] = S2;
        }
    }
    grid_barrier(&bar[0], NBLK);

    // ---------------- Phase 1: GN + 1x1 conv projections (768 units) -------
    if (bid < 768) {
        int w = t >> 6, lane = t & 63, n16 = lane & 15, quad = lane >> 4;
        int bx = bid & 127, by = (bid >> 7) & 1, bz = bid >> 8;
        int dtile = bx * 32;
        int b = by, z = bz;

        const float* in; const float* Wm; const float* gamma; const float* beta;
        int sel = 1, donorm = 1; float oscale = 1.f;
        if (z == 0)      { in = x;   Wm = Wq; gamma = gq;   beta = bq;   sel = 0;
                           oscale = 0.17677669529663689f * 1.4426950408889634f; }
        else if (z == 1) { in = ctx; Wm = Wk; gamma = gctx; beta = bctx; }
        else             { in = ctx; Wm = Wv; gamma = 0;    beta = 0;    donorm = 0; }

        unsigned short* Xs = (unsigned short*)SMEM;   // [32 d][136 c]

        // stage 128c x 32d tile: GN + bf16 + 4x4 register transpose
        {
            int c0 = (t >> 3) * 4, d4 = (t & 7) * 4;
            const float* inb = in + (size_t)b * (C * L);
            float scg[4], shg[4];
            if (donorm) {
                int gl = (sel * 256 + (b * 32 + (c0 >> 2)) * 4) * 2;
                float S  = stats[gl] + stats[gl + 2] + stats[gl + 4] + stats[gl + 6];
                float S2 = stats[gl + 1] + stats[gl + 3] + stats[gl + 5] + stats[gl + 7];
                float mean = S * (1.f / 16384.f);
                float var  = S2 * (1.f / 16384.f) - mean * mean;
                float inv  = rsqrtf(var + EPSV);
                #pragma unroll
                for (int j = 0; j < 4; j++) {
                    scg[j] = inv * gamma[c0 + j];
                    shg[j] = beta[c0 + j] - mean * scg[j];
                }
            } else {
                #pragma unroll
                for (int j = 0; j < 4; j++) { scg[j] = 1.f; shg[j] = 0.f; }
            }
            float vv[4][4];
            #pragma unroll
            for (int j = 0; j < 4; j++) {
                float4 v = *(const float4*)(inb + (size_t)(c0 + j) * L + dtile + d4);
                vv[j][0] = v.x * scg[j] + shg[j]; vv[j][1] = v.y * scg[j] + shg[j];
                vv[j][2] = v.z * scg[j] + shg[j]; vv[j][3] = v.w * scg[j] + shg[j];
            }
            #pragma unroll
            for (int i = 0; i < 4; i++) {
                uint2 pk;
                pk.x = pack2bf(vv[0][i], vv[1][i]);
                pk.y = pack2bf(vv[2][i], vv[3][i]);
                *(uint2*)&Xs[(d4 + i) * 136 + c0] = pk;
            }
        }

        // W A-fragments: wave w covers o-strips {w, w+4}; A[m=o][k=c]
        bf16x8 wa[2][4];
        #pragma unroll
        for (int os2 = 0; os2 < 2; os2++) {
            const float* wr = Wm + (size_t)(((w + os2 * 4) * 16) + n16) * C + quad * 8;
            #pragma unroll
            for (int kk = 0; kk < 4; kk++) {
                float4 a  = *(const float4*)(wr + kk * 32);
                float4 b2 = *(const float4*)(wr + kk * 32 + 4);
                unsigned u4[4] = { pack2bf(a.x, a.y),  pack2bf(a.z, a.w),
                                   pack2bf(b2.x, b2.y), pack2bf(b2.z, b2.w) };
                __builtin_memcpy(&wa[os2][kk], u4, 16);
            }
        }
        __syncthreads();

        f32x4 zero = {0.f, 0.f, 0.f, 0.f};
        f32x4 acc[2][2];
        acc[0][0] = zero; acc[0][1] = zero; acc[1][0] = zero; acc[1][1] = zero;
        #pragma unroll
        for (int kk = 0; kk < 4; kk++) {
            #pragma unroll
            for (int dg = 0; dg < 2; dg++) {
                bf16x8 xb;
                uint4 u = *(const uint4*)&Xs[(dg * 16 + n16) * 136 + kk * 32 + quad * 8];
                __builtin_memcpy(&xb, &u, 16);
                acc[0][dg] = __builtin_amdgcn_mfma_f32_16x16x32_bf16(wa[0][kk], xb, acc[0][dg], 0, 0, 0);
                acc[1][dg] = __builtin_amdgcn_mfma_f32_16x16x32_bf16(wa[1][kk], xb, acc[1][dg], 0, 0, 0);
            }
        }

        // epilogue: lane holds D[o = (w+os2*4)*16+quad*4+r][d = dtile+dg*16+n16]
        #pragma unroll
        for (int os2 = 0; os2 < 2; os2++) {
            int o = ((w + os2 * 4) * 16) + quad * 4;
            int h = o >> 5, c32 = o & 31;
            #pragma unroll
            for (int dg = 0; dg < 2; dg++) {
                int d = dtile + dg * 16 + n16;
                if (z < 2) {
                    unsigned short* outp = (z == 0) ? Qt : Kt;
                    uint2 pk;
                    pk.x = pack2bf(acc[os2][dg][0] * oscale, acc[os2][dg][1] * oscale);
                    pk.y = pack2bf(acc[os2][dg][2] * oscale, acc[os2][dg][3] * oscale);
                    *(uint2*)(outp + ((size_t)(b * NH + h) * L + d) * HD + c32) = pk;
                } else {
                    unsigned short* vb = Vsw + (size_t)(b * NH + h) * (L * HD)
                                       + (size_t)(d >> 3) * 256 + (d & 7);
                    #pragma unroll
                    for (int r = 0; r < 4; r++) {
                        __hip_bfloat16 hv = __float2bfloat16(acc[os2][dg][r]);
                        unsigned short us; __builtin_memcpy(&us, &hv, 2);
                        vb[(c32 + r) * 8] = us;
                    }
                }
            }
        }
    }
    grid_barrier(&bar[1], NBLK);

    // ---------------- Phase 2: flash attention (1024 units) -----------------
    {
        unsigned short* Ps = (unsigned short*)SMEM;   // [4 waves][2 sp][1152]
        int w = t >> 6, lane = t & 63;
        int n16 = lane & 15, quad = lane >> 4;
        int bh = bid & 7;
        int qbase = ((bid >> 3) & 31) * 128 + w * 32;
        int ks = bid >> 8;
        size_t hb = (size_t)bh * (L * HD);

        bf16x8 qf[2];
        #pragma unroll
        for (int sp = 0; sp < 2; sp++) {
            uint4 u = *(const uint4*)(Qt + hb + (size_t)(qbase + sp * 16 + n16) * HD + quad * 8);
            __builtin_memcpy(&qf[sp], &u, 16);
        }

        bf16x8 onesf;
        #pragma unroll
        for (int j = 0; j < 8; j++) onesf[j] = (short)0x3F80;

        const unsigned short* kfp = Kt + hb + (size_t)n16 * HD + quad * 8;
        const unsigned short* vfp = Vsw + hb + quad * 256 + n16 * 8;

        int e0 = ks * (L / KS);

        bf16x8 ka[2][4], va[2][4];
        #pragma unroll
        for (int et = 0; et < 4; et++) {
            uint4 u = *(const uint4*)(kfp + (size_t)(e0 + et * 16) * HD);
            __builtin_memcpy(&ka[0][et], &u, 16);
        }
        #pragma unroll
        for (int es = 0; es < 2; es++)
            #pragma unroll
            for (int f = 0; f < 2; f++) {
                uint4 u = *(const uint4*)(vfp + (size_t)(e0 + es * 32) * 32 + f * 128);
                __builtin_memcpy(&va[0][es * 2 + f], &u, 16);
            }

        f32x4 zero = {0.f, 0.f, 0.f, 0.f};
        f32x4 oacc[2][2], lacc[2];
        oacc[0][0] = zero; oacc[0][1] = zero; oacc[1][0] = zero; oacc[1][1] = zero;
        lacc[0] = zero; lacc[1] = zero;

        #pragma unroll 2
        for (int kt = 0; kt < L / KS / 64; kt++) {
            int cur = kt & 1, nxt = cur ^ 1;
            int enxt = e0 + (kt + 1) * 64;
            #pragma unroll
            for (int et = 0; et < 4; et++) {
                uint4 u = *(const uint4*)(kfp + (size_t)(enxt + et * 16) * HD);
                __builtin_memcpy(&ka[nxt][et], &u, 16);
            }
            #pragma unroll
            for (int es = 0; es < 2; es++)
                #pragma unroll
                for (int f = 0; f < 2; f++) {
                    uint4 u = *(const uint4*)(vfp + (size_t)(enxt + es * 32) * 32 + f * 128);
                    __builtin_memcpy(&va[nxt][es * 2 + f], &u, 16);
                }

            #pragma unroll
            for (int sp = 0; sp < 2; sp++) {
                f32x4 s[4];
                #pragma unroll
                for (int et = 0; et < 4; et++)
                    s[et] = __builtin_amdgcn_mfma_f32_16x16x32_bf16(ka[cur][et], qf[sp], zero, 0, 0, 0);
                unsigned short* pw = Ps + ((w * 2 + sp) * 1152) + n16 * 72;
                #pragma unroll
                for (int et = 0; et < 4; et++) {
                    uint2 pk;
                    pk.x = exp2pk(s[et][0], s[et][1]);
                    pk.y = exp2pk(s[et][2], s[et][3]);
                    *(uint2*)(pw + et * 16 + quad * 4) = pk;
                }
            }

            #pragma unroll
            for (int sp = 0; sp < 2; sp++) {
                unsigned short* pw = Ps + ((w * 2 + sp) * 1152) + n16 * 72;
                #pragma unroll
                for (int es = 0; es < 2; es++) {
                    bf16x8 pf;
                    uint4 u = *(const uint4*)(pw + es * 32 + quad * 8);
                    __builtin_memcpy(&pf, &u, 16);
                    oacc[sp][0] = __builtin_amdgcn_mfma_f32_16x16x32_bf16(va[cur][es * 2 + 0], pf, oacc[sp][0], 0, 0, 0);
                    oacc[sp][1] = __builtin_amdgcn_mfma_f32_16x16x32_bf16(va[cur][es * 2 + 1], pf, oacc[sp][1], 0, 0, 0);
                    lacc[sp]    = __builtin_amdgcn_mfma_f32_16x16x32_bf16(onesf, pf, lacc[sp], 0, 0, 0);
                }
            }
        }

        #pragma unroll
        for (int sp = 0; sp < 2; sp++) {
            int dq = qbase + sp * 16 + n16;
            unsigned short* po = Po + ((size_t)(bh * KS + ks) * L + dq) * 32;
            uint2 pk0, pk1;
            pk0.x = pack2bf(oacc[sp][0][0], oacc[sp][0][1]);
            pk0.y = pack2bf(oacc[sp][0][2], oacc[sp][0][3]);
            pk1.x = pack2bf(oacc[sp][1][0], oacc[sp][1][1]);
            pk1.y = pack2bf(oacc[sp][1][2], oacc[sp][1][3]);
            *(uint2*)(po + quad * 4)      = pk0;
            *(uint2*)(po + 16 + quad * 4) = pk1;
            if (quad == 0)
                Pl[(size_t)(bh * KS + ks) * L + dq] = lacc[sp][0];
        }
    }
    grid_barrier(&bar[2], NBLK);

    // ---------------- Phase 3: split-K combine + out GEMM + residual --------
    if (bid < 512) {
        int w = t >> 6, lane = t & 63, n16 = lane & 15, quad = lane >> 4;
        int dtile = (bid & 255) * 16;
        int b = bid >> 8;

        float* Ot = (float*)SMEM;                   // [128 o][20 d]
        unsigned short* Xs = (unsigned short*)SMEM; // [16 d][136 c]

        // stage: combine KS bf16 partials, normalize, bf16, [d][c] layout
        {
            int d_l = t >> 4, c0 = (t & 15) * 8;
            int dq = dtile + d_l;
            int bh = b * NH + (c0 >> 5);
            int c32 = c0 & 31;
            float l = 0.f;
            float o8[8] = {0.f, 0.f, 0.f, 0.f, 0.f, 0.f, 0.f, 0.f};
            #pragma unroll
            for (int ks = 0; ks < KS; ks++) {
                size_t base = (size_t)(bh * KS + ks) * L + dq;
                l += Pl[base];
                uint4 u = *(const uint4*)(Po + base * 32 + c32);
                o8[0] += bf_lo(u.x); o8[1] += bf_hi(u.x);
                o8[2] += bf_lo(u.y); o8[3] += bf_hi(u.y);
                o8[4] += bf_lo(u.z); o8[5] += bf_hi(u.z);
                o8[6] += bf_lo(u.w); o8[7] += bf_hi(u.w);
            }
            float rl = 1.f / l;
            uint4 pk;
            pk.x = pack2bf(o8[0] * rl, o8[1] * rl);
            pk.y = pack2bf(o8[2] * rl, o8[3] * rl);
            pk.z = pack2bf(o8[4] * rl, o8[5] * rl);
            pk.w = pack2bf(o8[6] * rl, o8[7] * rl);
            *(uint4*)&Xs[d_l * 136 + c0] = pk;
        }

        // Wout A-fragments
        bf16x8 wa[2][4];
        #pragma unroll
        for (int os2 = 0; os2 < 2; os2++) {
            const float* wr = Wout + (size_t)(((w + os2 * 4) * 16) + n16) * C + quad * 8;
            #pragma unroll
            for (int kk = 0; kk < 4; kk++) {
                float4 a  = *(const float4*)(wr + kk * 32);
                float4 b2 = *(const float4*)(wr + kk * 32 + 4);
                unsigned u4[4] = { pack2bf(a.x, a.y),  pack2bf(a.z, a.w),
                                   pack2bf(b2.x, b2.y), pack2bf(b2.z, b2.w) };
                __builtin_memcpy(&wa[os2][kk], u4, 16);
            }
        }
        __syncthreads();

        f32x4 zero = {0.f, 0.f, 0.f, 0.f};
        f32x4 acc[2];
        acc[0] = zero; acc[1] = zero;
        #pragma unroll
        for (int kk = 0; kk < 4; kk++) {
            bf16x8 xb;
            uint4 u = *(const uint4*)&Xs[n16 * 136 + kk * 32 + quad * 8];
            __builtin_memcpy(&xb, &u, 16);
            acc[0] = __builtin_amdgcn_mfma_f32_16x16x32_bf16(wa[0][kk], xb, acc[0], 0, 0, 0);
            acc[1] = __builtin_amdgcn_mfma_f32_16x16x32_bf16(wa[1][kk], xb, acc[1], 0, 0, 0);
        }
        __syncthreads();   // Xs reads done before Ot overwrite

        // acc -> Ot[o][d] (fp32, stride 20)
        #pragma unroll
        for (int os2 = 0; os2 < 2; os2++) {
            int o = ((w + os2 * 4) * 16) + quad * 4;
            #pragma unroll
            for (int r = 0; r < 4; r++)
                Ot[(o + r) * 20 + n16] = acc[os2][r];
        }
        __syncthreads();

        // epilogue: coalesced residual + store
        float al = alpha[0];
        int o = t >> 1, dh = (t & 1) * 8;
        float bo = bout[o];
        const float* xb2 = x + ((size_t)b * C + o) * L + dtile + dh;
        float* ob = out + ((size_t)b * C + o) * L + dtile + dh;
        #pragma unroll
        for (int jj = 0; jj < 2; jj++) {
            float4 a  = *(const float4*)&Ot[o * 20 + dh + jj * 4];
            float4 xv = *(const float4*)(xb2 + jj * 4);
            float4 r;
            r.x = xv.x + al * (a.x + bo);
            r.y = xv.y + al * (a.y + bo);
            r.z = xv.z + al * (a.z + bo);
            r.w = xv.w + al * (a.w + bo);
            *(float4*)(ob + jj * 4) = r;
        }
    }
}

// ---------------------------------------------------------------------------
extern "C" void kernel_launch(void* const* d_in, const int* in_sizes, int n_in,
                              void* d_out, int out_size, void* d_ws, size_t ws_size,
                              hipStream_t stream) {
    const float* x     = (const float*)d_in[0];
    const float* ctx   = (const float*)d_in[1];
    const float* gq    = (const float*)d_in[2];
    const float* bq    = (const float*)d_in[3];
    const float* gctx  = (const float*)d_in[4];
    const float* bctx  = (const float*)d_in[5];
    const float* Wq    = (const float*)d_in[6];
    const float* Wk    = (const float*)d_in[7];
    const float* Wv    = (const float*)d_in[8];
    const float* Wout  = (const float*)d_in[9];
    const float* bout  = (const float*)d_in[10];
    const float* alpha = (const float*)d_in[11];
    float* out = (float*)d_out;

    char* ws = (char*)d_ws;
    unsigned short* Qt  = (unsigned short*)(ws);              //  2 MB
    unsigned short* Kt  = (unsigned short*)(ws + 2097152);    //  2 MB
    unsigned short* Vsw = (unsigned short*)(ws + 4194304);    //  2 MB
    unsigned short* Po  = (unsigned short*)(ws + 6291456);    //  8 MB (bf16, KS=4)
    float*          Pl  = (float*)(ws + 14680064);            //  512 KB
    float*          stats = (float*)(ws + 15204352);          //  4 KB (512 x 2)
    unsigned*       bar = (unsigned*)(ws + 15728640);         //  64 B barrier ctrs

    // zero barrier counters (capture-safe stream op; re-runs every iteration)
    hipMemsetAsync(bar, 0, 64, stream);
    fused_kernel<<<NBLK, 256, 0, stream>>>(x, ctx, gq, bq, gctx, bctx,
                                           Wq, Wk, Wv, Wout, bout, alpha,
                                           Qt, Kt, Vsw, Po, Pl, stats, bar, out);
}

// Round 8
// 129.406 us; speedup vs baseline: 3.6809x; 3.1186x over previous
//
#include <hip/hip_runtime.h>
#include <hip/hip_bf16.h>
#include <math.h>

#define L 4096          // H*W
#define C 128
#define NH 4
#define HD 32
#define KS 4            // flash split-K factor
#define EPSV 1e-5f
#define NBLK 1024u      // fused grid: 4 blocks/CU x 256 CUs (flash's proven config)
#define BAR_U 2048      // uints per barrier struct (32 ctrs @128B stride, root, flag)

typedef short bf16x8 __attribute__((ext_vector_type(8)));
typedef float f32x4 __attribute__((ext_vector_type(4)));

static __device__ __forceinline__ unsigned pack2bf(float a, float b) {
    __hip_bfloat162 h = __float22bfloat162_rn(make_float2(a, b));
    unsigned u; __builtin_memcpy(&u, &h, 4); return u;
}
static __device__ __forceinline__ float bf_lo(unsigned u) {
    unsigned v = u << 16; float f; __builtin_memcpy(&f, &v, 4); return f;
}
static __device__ __forceinline__ float bf_hi(unsigned u) {
    unsigned v = u & 0xffff0000u; float f; __builtin_memcpy(&f, &v, 4); return f;
}
// Fused Schraudolph-2^x + bf16-pack (passed r5-r7, absmax 0.015625).
static __device__ __forceinline__ unsigned exp2pk(float a, float b) {
    float fa = fmaf(a, 128.f, 8404858.f);
    float fb = fmaf(b, 128.f, 8404858.f);
    unsigned ua, ub;
    __builtin_memcpy(&ua, &fa, 4);
    __builtin_memcpy(&ub, &fb, 4);
    return __builtin_amdgcn_perm(ub, ua, 0x05040100);  // (ua&0xffff)|(ub<<16)
}

// Agent-coherent relaxed stores: write THROUGH the (non-XCD-coherent) L2 to
// the MALL coherence point. Consumers' cached loads then first-touch current
// data (all L2s are clean at kernel start via the prior dispatch's implicit
// writeback-invalidate). This removes ALL fence/cache-maintenance ops from
// the grid barrier — r6/r7's 300us cost was per-block agent release/acquire
// (L2 wb/inv tag-scans x 6144 per iteration).
static __device__ __forceinline__ void st8_agent(void* p, uint2 v) {
    unsigned long long u; __builtin_memcpy(&u, &v, 8);
    __hip_atomic_store((unsigned long long*)p, u, __ATOMIC_RELAXED, __HIP_MEMORY_SCOPE_AGENT);
}
static __device__ __forceinline__ void stf_agent(float* p, float v) {
    __hip_atomic_store(p, v, __ATOMIC_RELAXED, __HIP_MEMORY_SCOPE_AGENT);
}
static __device__ __forceinline__ void st2_agent(unsigned short* p, unsigned short v) {
    __hip_atomic_store(p, v, __ATOMIC_RELAXED, __HIP_MEMORY_SCOPE_AGENT);
}

// Fence-free grid barrier: vmcnt(0) drains agent store-acks (= visible at
// MALL), then a two-level RELAXED arrive tree (32 spread counters -> root ->
// write-once flag; caps same-address RMW chains at 32) and a read-only
// relaxed flag spin. No release/acquire anywhere.
static __device__ __forceinline__ void grid_barrier(unsigned* base) {
    __syncthreads();
    if (threadIdx.x == 0) {
        asm volatile("s_waitcnt vmcnt(0)" ::: "memory");
        unsigned* ctr  = base + (blockIdx.x & 31) * 32;   // 128B stride
        unsigned* root = base + 1024;
        unsigned* flag = base + 1056;
        unsigned prev = __hip_atomic_fetch_add(ctr, 1u, __ATOMIC_RELAXED, __HIP_MEMORY_SCOPE_AGENT);
        if (prev == 31u) {                                // last of 32 in sub-group
            unsigned p2 = __hip_atomic_fetch_add(root, 1u, __ATOMIC_RELAXED, __HIP_MEMORY_SCOPE_AGENT);
            if (p2 == 31u)
                __hip_atomic_store(flag, 1u, __ATOMIC_RELAXED, __HIP_MEMORY_SCOPE_AGENT);
        }
        while (__hip_atomic_load(flag, __ATOMIC_RELAXED, __HIP_MEMORY_SCOPE_AGENT) == 0u)
            __builtin_amdgcn_s_sleep(8);
    }
    __syncthreads();
}

// ---------------------------------------------------------------------------
// Fused pipeline: [gn_stats | proj | flash | final] with 3 fence-free grid
// barriers. Inter-phase workspace stores are agent-coherent (write-through);
// all other loads/stores unchanged. Phase bodies identical to r5 production.
__global__ __launch_bounds__(256, 4) void fused_kernel(
    const float* __restrict__ x, const float* __restrict__ ctx,
    const float* __restrict__ gq, const float* __restrict__ bq,
    const float* __restrict__ gctx, const float* __restrict__ bctx,
    const float* __restrict__ Wq, const float* __restrict__ Wk,
    const float* __restrict__ Wv, const float* __restrict__ Wout,
    const float* __restrict__ bout, const float* __restrict__ alpha,
    unsigned short* __restrict__ Qt, unsigned short* __restrict__ Kt,
    unsigned short* __restrict__ Vsw, unsigned short* __restrict__ Po,
    float* __restrict__ Pl, float* __restrict__ stats,
    unsigned* __restrict__ bar, float* __restrict__ out)
{
    __shared__ __attribute__((aligned(16))) unsigned char SMEM[4 * 2 * 1152 * 2];
    int bid = blockIdx.x;
    int t = threadIdx.x;

    // ---------------- Phase 0: GroupNorm partial sums (512 units) ----------
    if (bid < 512) {
        const float* in = (bid < 256) ? x : ctx;
        int idx = bid & 255;                   // (b*32+g)*4 + qtr
        const float4* p = (const float4*)(in + (size_t)(idx >> 2) * 16384
                                             + (size_t)(idx & 3) * 4096);
        float s = 0.f, s2 = 0.f;
        #pragma unroll
        for (int rr = 0; rr < 4; rr++) {
            float4 v = p[t + rr * 256];
            s  += v.x + v.y + v.z + v.w;
            s2 += v.x*v.x + v.y*v.y + v.z*v.z + v.w*v.w;
        }
        #pragma unroll
        for (int m = 32; m >= 1; m >>= 1) {
            s  += __shfl_xor(s, m);
            s2 += __shfl_xor(s2, m);
        }
        float (*wsum)[2] = (float(*)[2])SMEM;
        int w = t >> 6;
        if ((t & 63) == 0) { wsum[w][0] = s; wsum[w][1] = s2; }
        __syncthreads();
        if (t == 0) {
            float S  = wsum[0][0] + wsum[1][0] + wsum[2][0] + wsum[3][0];
            float S2 = wsum[0][1] + wsum[1][1] + wsum[2][1] + wsum[3][1];
            uint2 pk;
            __builtin_memcpy(&pk.x, &S, 4);
            __builtin_memcpy(&pk.y, &S2, 4);
            st8_agent(&stats[bid * 2], pk);
        }
    }
    grid_barrier(bar + 0 * BAR_U);

    // ---------------- Phase 1: GN + 1x1 conv projections (768 units) -------
    if (bid < 768) {
        int w = t >> 6, lane = t & 63, n16 = lane & 15, quad = lane >> 4;
        int bx = bid & 127, by = (bid >> 7) & 1, bz = bid >> 8;
        int dtile = bx * 32;
        int b = by, z = bz;

        const float* in; const float* Wm; const float* gamma; const float* beta;
        int sel = 1, donorm = 1; float oscale = 1.f;
        if (z == 0)      { in = x;   Wm = Wq; gamma = gq;   beta = bq;   sel = 0;
                           oscale = 0.17677669529663689f * 1.4426950408889634f; }
        else if (z == 1) { in = ctx; Wm = Wk; gamma = gctx; beta = bctx; }
        else             { in = ctx; Wm = Wv; gamma = 0;    beta = 0;    donorm = 0; }

        unsigned short* Xs = (unsigned short*)SMEM;   // [32 d][136 c]

        // stage 128c x 32d tile: GN + bf16 + 4x4 register transpose
        {
            int c0 = (t >> 3) * 4, d4 = (t & 7) * 4;
            const float* inb = in + (size_t)b * (C * L);
            float scg[4], shg[4];
            if (donorm) {
                int gl = (sel * 256 + (b * 32 + (c0 >> 2)) * 4) * 2;
                float S  = stats[gl] + stats[gl + 2] + stats[gl + 4] + stats[gl + 6];
                float S2 = stats[gl + 1] + stats[gl + 3] + stats[gl + 5] + stats[gl + 7];
                float mean = S * (1.f / 16384.f);
                float var  = S2 * (1.f / 16384.f) - mean * mean;
                float inv  = rsqrtf(var + EPSV);
                #pragma unroll
                for (int j = 0; j < 4; j++) {
                    scg[j] = inv * gamma[c0 + j];
                    shg[j] = beta[c0 + j] - mean * scg[j];
                }
            } else {
                #pragma unroll
                for (int j = 0; j < 4; j++) { scg[j] = 1.f; shg[j] = 0.f; }
            }
            float vv[4][4];
            #pragma unroll
            for (int j = 0; j < 4; j++) {
                float4 v = *(const float4*)(inb + (size_t)(c0 + j) * L + dtile + d4);
                vv[j][0] = v.x * scg[j] + shg[j]; vv[j][1] = v.y * scg[j] + shg[j];
                vv[j][2] = v.z * scg[j] + shg[j]; vv[j][3] = v.w * scg[j] + shg[j];
            }
            #pragma unroll
            for (int i = 0; i < 4; i++) {
                uint2 pk;
                pk.x = pack2bf(vv[0][i], vv[1][i]);
                pk.y = pack2bf(vv[2][i], vv[3][i]);
                *(uint2*)&Xs[(d4 + i) * 136 + c0] = pk;
            }
        }

        // W A-fragments: wave w covers o-strips {w, w+4}; A[m=o][k=c]
        bf16x8 wa[2][4];
        #pragma unroll
        for (int os2 = 0; os2 < 2; os2++) {
            const float* wr = Wm + (size_t)(((w + os2 * 4) * 16) + n16) * C + quad * 8;
            #pragma unroll
            for (int kk = 0; kk < 4; kk++) {
                float4 a  = *(const float4*)(wr + kk * 32);
                float4 b2 = *(const float4*)(wr + kk * 32 + 4);
                unsigned u4[4] = { pack2bf(a.x, a.y),  pack2bf(a.z, a.w),
                                   pack2bf(b2.x, b2.y), pack2bf(b2.z, b2.w) };
                __builtin_memcpy(&wa[os2][kk], u4, 16);
            }
        }
        __syncthreads();

        f32x4 zero = {0.f, 0.f, 0.f, 0.f};
        f32x4 acc[2][2];
        acc[0][0] = zero; acc[0][1] = zero; acc[1][0] = zero; acc[1][1] = zero;
        #pragma unroll
        for (int kk = 0; kk < 4; kk++) {
            #pragma unroll
            for (int dg = 0; dg < 2; dg++) {
                bf16x8 xb;
                uint4 u = *(const uint4*)&Xs[(dg * 16 + n16) * 136 + kk * 32 + quad * 8];
                __builtin_memcpy(&xb, &u, 16);
                acc[0][dg] = __builtin_amdgcn_mfma_f32_16x16x32_bf16(wa[0][kk], xb, acc[0][dg], 0, 0, 0);
                acc[1][dg] = __builtin_amdgcn_mfma_f32_16x16x32_bf16(wa[1][kk], xb, acc[1][dg], 0, 0, 0);
            }
        }

        // epilogue (agent-coherent stores): D[o][d]
        #pragma unroll
        for (int os2 = 0; os2 < 2; os2++) {
            int o = ((w + os2 * 4) * 16) + quad * 4;
            int h = o >> 5, c32 = o & 31;
            #pragma unroll
            for (int dg = 0; dg < 2; dg++) {
                int d = dtile + dg * 16 + n16;
                if (z < 2) {
                    unsigned short* outp = (z == 0) ? Qt : Kt;
                    uint2 pk;
                    pk.x = pack2bf(acc[os2][dg][0] * oscale, acc[os2][dg][1] * oscale);
                    pk.y = pack2bf(acc[os2][dg][2] * oscale, acc[os2][dg][3] * oscale);
                    st8_agent(outp + ((size_t)(b * NH + h) * L + d) * HD + c32, pk);
                } else {
                    unsigned short* vb = Vsw + (size_t)(b * NH + h) * (L * HD)
                                       + (size_t)(d >> 3) * 256 + (d & 7);
                    #pragma unroll
                    for (int r = 0; r < 4; r++) {
                        __hip_bfloat16 hv = __float2bfloat16(acc[os2][dg][r]);
                        unsigned short us; __builtin_memcpy(&us, &hv, 2);
                        st2_agent(&vb[(c32 + r) * 8], us);
                    }
                }
            }
        }
    }
    grid_barrier(bar + 1 * BAR_U);

    // ---------------- Phase 2: flash attention (1024 units) -----------------
    {
        unsigned short* Ps = (unsigned short*)SMEM;   // [4 waves][2 sp][1152]
        int w = t >> 6, lane = t & 63;
        int n16 = lane & 15, quad = lane >> 4;
        int bh = bid & 7;
        int qbase = ((bid >> 3) & 31) * 128 + w * 32;
        int ks = bid >> 8;
        size_t hb = (size_t)bh * (L * HD);

        bf16x8 qf[2];
        #pragma unroll
        for (int sp = 0; sp < 2; sp++) {
            uint4 u = *(const uint4*)(Qt + hb + (size_t)(qbase + sp * 16 + n16) * HD + quad * 8);
            __builtin_memcpy(&qf[sp], &u, 16);
        }

        bf16x8 onesf;
        #pragma unroll
        for (int j = 0; j < 8; j++) onesf[j] = (short)0x3F80;

        const unsigned short* kfp = Kt + hb + (size_t)n16 * HD + quad * 8;
        const unsigned short* vfp = Vsw + hb + quad * 256 + n16 * 8;

        int e0 = ks * (L / KS);

        bf16x8 ka[2][4], va[2][4];
        #pragma unroll
        for (int et = 0; et < 4; et++) {
            uint4 u = *(const uint4*)(kfp + (size_t)(e0 + et * 16) * HD);
            __builtin_memcpy(&ka[0][et], &u, 16);
        }
        #pragma unroll
        for (int es = 0; es < 2; es++)
            #pragma unroll
            for (int f = 0; f < 2; f++) {
                uint4 u = *(const uint4*)(vfp + (size_t)(e0 + es * 32) * 32 + f * 128);
                __builtin_memcpy(&va[0][es * 2 + f], &u, 16);
            }

        f32x4 zero = {0.f, 0.f, 0.f, 0.f};
        f32x4 oacc[2][2], lacc[2];
        oacc[0][0] = zero; oacc[0][1] = zero; oacc[1][0] = zero; oacc[1][1] = zero;
        lacc[0] = zero; lacc[1] = zero;

        #pragma unroll 2
        for (int kt = 0; kt < L / KS / 64; kt++) {
            int cur = kt & 1, nxt = cur ^ 1;
            int enxt = e0 + (kt + 1) * 64;
            #pragma unroll
            for (int et = 0; et < 4; et++) {
                uint4 u = *(const uint4*)(kfp + (size_t)(enxt + et * 16) * HD);
                __builtin_memcpy(&ka[nxt][et], &u, 16);
            }
            #pragma unroll
            for (int es = 0; es < 2; es++)
                #pragma unroll
                for (int f = 0; f < 2; f++) {
                    uint4 u = *(const uint4*)(vfp + (size_t)(enxt + es * 32) * 32 + f * 128);
                    __builtin_memcpy(&va[nxt][es * 2 + f], &u, 16);
                }

            #pragma unroll
            for (int sp = 0; sp < 2; sp++) {
                f32x4 s[4];
                #pragma unroll
                for (int et = 0; et < 4; et++)
                    s[et] = __builtin_amdgcn_mfma_f32_16x16x32_bf16(ka[cur][et], qf[sp], zero, 0, 0, 0);
                unsigned short* pw = Ps + ((w * 2 + sp) * 1152) + n16 * 72;
                #pragma unroll
                for (int et = 0; et < 4; et++) {
                    uint2 pk;
                    pk.x = exp2pk(s[et][0], s[et][1]);
                    pk.y = exp2pk(s[et][2], s[et][3]);
                    *(uint2*)(pw + et * 16 + quad * 4) = pk;
                }
            }

            #pragma unroll
            for (int sp = 0; sp < 2; sp++) {
                unsigned short* pw = Ps + ((w * 2 + sp) * 1152) + n16 * 72;
                #pragma unroll
                for (int es = 0; es < 2; es++) {
                    bf16x8 pf;
                    uint4 u = *(const uint4*)(pw + es * 32 + quad * 8);
                    __builtin_memcpy(&pf, &u, 16);
                    oacc[sp][0] = __builtin_amdgcn_mfma_f32_16x16x32_bf16(va[cur][es * 2 + 0], pf, oacc[sp][0], 0, 0, 0);
                    oacc[sp][1] = __builtin_amdgcn_mfma_f32_16x16x32_bf16(va[cur][es * 2 + 1], pf, oacc[sp][1], 0, 0, 0);
                    lacc[sp]    = __builtin_amdgcn_mfma_f32_16x16x32_bf16(onesf, pf, lacc[sp], 0, 0, 0);
                }
            }
        }

        #pragma unroll
        for (int sp = 0; sp < 2; sp++) {
            int dq = qbase + sp * 16 + n16;
            unsigned short* po = Po + ((size_t)(bh * KS + ks) * L + dq) * 32;
            uint2 pk0, pk1;
            pk0.x = pack2bf(oacc[sp][0][0], oacc[sp][0][1]);
            pk0.y = pack2bf(oacc[sp][0][2], oacc[sp][0][3]);
            pk1.x = pack2bf(oacc[sp][1][0], oacc[sp][1][1]);
            pk1.y = pack2bf(oacc[sp][1][2], oacc[sp][1][3]);
            st8_agent(po + quad * 4,      pk0);
            st8_agent(po + 16 + quad * 4, pk1);
            if (quad == 0)
                stf_agent(&Pl[(size_t)(bh * KS + ks) * L + dq], lacc[sp][0]);
        }
    }
    grid_barrier(bar + 2 * BAR_U);

    // ---------------- Phase 3: split-K combine + out GEMM + residual --------
    if (bid < 512) {
        int w = t >> 6, lane = t & 63, n16 = lane & 15, quad = lane >> 4;
        int dtile = (bid & 255) * 16;
        int b = bid >> 8;

        float* Ot = (float*)SMEM;                   // [128 o][20 d]
        unsigned short* Xs = (unsigned short*)SMEM; // [16 d][136 c]

        // stage: combine KS bf16 partials, normalize, bf16, [d][c] layout
        {
            int d_l = t >> 4, c0 = (t & 15) * 8;
            int dq = dtile + d_l;
            int bh = b * NH + (c0 >> 5);
            int c32 = c0 & 31;
            float l = 0.f;
            float o8[8] = {0.f, 0.f, 0.f, 0.f, 0.f, 0.f, 0.f, 0.f};
            #pragma unroll
            for (int ks = 0; ks < KS; ks++) {
                size_t base = (size_t)(bh * KS + ks) * L + dq;
                l += Pl[base];
                uint4 u = *(const uint4*)(Po + base * 32 + c32);
                o8[0] += bf_lo(u.x); o8[1] += bf_hi(u.x);
                o8[2] += bf_lo(u.y); o8[3] += bf_hi(u.y);
                o8[4] += bf_lo(u.z); o8[5] += bf_hi(u.z);
                o8[6] += bf_lo(u.w); o8[7] += bf_hi(u.w);
            }
            float rl = 1.f / l;
            uint4 pk;
            pk.x = pack2bf(o8[0] * rl, o8[1] * rl);
            pk.y = pack2bf(o8[2] * rl, o8[3] * rl);
            pk.z = pack2bf(o8[4] * rl, o8[5] * rl);
            pk.w = pack2bf(o8[6] * rl, o8[7] * rl);
            *(uint4*)&Xs[d_l * 136 + c0] = pk;
        }

        // Wout A-fragments
        bf16x8 wa[2][4];
        #pragma unroll
        for (int os2 = 0; os2 < 2; os2++) {
            const float* wr = Wout + (size_t)(((w + os2 * 4) * 16) + n16) * C + quad * 8;
            #pragma unroll
            for (int kk = 0; kk < 4; kk++) {
                float4 a  = *(const float4*)(wr + kk * 32);
                float4 b2 = *(const float4*)(wr + kk * 32 + 4);
                unsigned u4[4] = { pack2bf(a.x, a.y),  pack2bf(a.z, a.w),
                                   pack2bf(b2.x, b2.y), pack2bf(b2.z, b2.w) };
                __builtin_memcpy(&wa[os2][kk], u4, 16);
            }
        }
        __syncthreads();

        f32x4 zero = {0.f, 0.f, 0.f, 0.f};
        f32x4 acc[2];
        acc[0] = zero; acc[1] = zero;
        #pragma unroll
        for (int kk = 0; kk < 4; kk++) {
            bf16x8 xb;
            uint4 u = *(const uint4*)&Xs[n16 * 136 + kk * 32 + quad * 8];
            __builtin_memcpy(&xb, &u, 16);
            acc[0] = __builtin_amdgcn_mfma_f32_16x16x32_bf16(wa[0][kk], xb, acc[0], 0, 0, 0);
            acc[1] = __builtin_amdgcn_mfma_f32_16x16x32_bf16(wa[1][kk], xb, acc[1], 0, 0, 0);
        }
        __syncthreads();   // Xs reads done before Ot overwrite

        // acc -> Ot[o][d] (fp32, stride 20)
        #pragma unroll
        for (int os2 = 0; os2 < 2; os2++) {
            int o = ((w + os2 * 4) * 16) + quad * 4;
            #pragma unroll
            for (int r = 0; r < 4; r++)
                Ot[(o + r) * 20 + n16] = acc[os2][r];
        }
        __syncthreads();

        // epilogue: coalesced residual + store (normal stores; end-of-kernel
        // flush publishes out)
        float al = alpha[0];
        int o = t >> 1, dh = (t & 1) * 8;
        float bo = bout[o];
        const float* xb2 = x + ((size_t)b * C + o) * L + dtile + dh;
        float* ob = out + ((size_t)b * C + o) * L + dtile + dh;
        #pragma unroll
        for (int jj = 0; jj < 2; jj++) {
            float4 a  = *(const float4*)&Ot[o * 20 + dh + jj * 4];
            float4 xv = *(const float4*)(xb2 + jj * 4);
            float4 r;
            r.x = xv.x + al * (a.x + bo);
            r.y = xv.y + al * (a.y + bo);
            r.z = xv.z + al * (a.z + bo);
            r.w = xv.w + al * (a.w + bo);
            *(float4*)(ob + jj * 4) = r;
        }
    }
}

// ---------------------------------------------------------------------------
extern "C" void kernel_launch(void* const* d_in, const int* in_sizes, int n_in,
                              void* d_out, int out_size, void* d_ws, size_t ws_size,
                              hipStream_t stream) {
    const float* x     = (const float*)d_in[0];
    const float* ctx   = (const float*)d_in[1];
    const float* gq    = (const float*)d_in[2];
    const float* bq    = (const float*)d_in[3];
    const float* gctx  = (const float*)d_in[4];
    const float* bctx  = (const float*)d_in[5];
    const float* Wq    = (const float*)d_in[6];
    const float* Wk    = (const float*)d_in[7];
    const float* Wv    = (const float*)d_in[8];
    const float* Wout  = (const float*)d_in[9];
    const float* bout  = (const float*)d_in[10];
    const float* alpha = (const float*)d_in[11];
    float* out = (float*)d_out;

    char* ws = (char*)d_ws;
    unsigned short* Qt  = (unsigned short*)(ws);              //  2 MB
    unsigned short* Kt  = (unsigned short*)(ws + 2097152);    //  2 MB
    unsigned short* Vsw = (unsigned short*)(ws + 4194304);    //  2 MB
    unsigned short* Po  = (unsigned short*)(ws + 6291456);    //  8 MB (bf16, KS=4)
    float*          Pl  = (float*)(ws + 14680064);            //  512 KB
    float*          stats = (float*)(ws + 15204352);          //  4 KB (512 x 2)
    unsigned*       bar = (unsigned*)(ws + 15728640);         //  24 KB barrier structs

    // zero barrier structs (capture-safe stream op; re-runs every iteration)
    hipMemsetAsync(bar, 0, 3 * BAR_U * sizeof(unsigned), stream);
    fused_kernel<<<NBLK, 256, 0, stream>>>(x, ctx, gq, bq, gctx, bctx,
                                           Wq, Wk, Wv, Wout, bout, alpha,
                                           Qt, Kt, Vsw, Po, Pl, stats, bar, out);
}